// Round 4
// baseline (115.367 us; speedup 1.0000x reference)
//
#include <hip/hip_runtime.h>

#define TPB 256

__global__ __launch_bounds__(TPB) void edge_mlp_kernel(
    const float* __restrict__ x,
    const float* __restrict__ w,
    const float* __restrict__ W1,
    const float* __restrict__ b1,
    const float* __restrict__ W2,
    const float* __restrict__ b2,
    const int* __restrict__ src,
    const int* __restrict__ dst,
    float* __restrict__ w_out,
    float* __restrict__ e_tilde,
    int E)
{
    // W1 padded to 12 floats/row (48B) so each row is 16B-aligned for b128 reads.
    __shared__ float sW1[40 * 12];
    __shared__ float sW2t[40 * 4];   // transposed: [j][o]
    __shared__ float sb1[40];
    __shared__ float sb2[4];
    __shared__ float s_et[4][64 * 7]; // per-wave e_tilde staging (transpose to coalesced)

    const int t = threadIdx.x;

    for (int i = t; i < 480; i += TPB) {
        int r = i / 12, c = i - r * 12;
        sW1[i] = (c < 10) ? W1[r * 10 + c] : 0.f;
    }
    for (int i = t; i < 160; i += TPB) {
        int j = i >> 2, o = i & 3;
        sW2t[i] = W2[o * 40 + j];
    }
    if (t < 40) sb1[t] = b1[t];
    if (t < 4)  sb2[t] = b2[t];
    __syncthreads();

    const int e    = blockIdx.x * TPB + t;
    const int wave = t >> 6;
    const int lane = t & 63;

    float mm[10];
    float a0 = 0.f, a1 = 0.f, a2 = 0.f, a3 = 0.f;
    mm[0] = mm[1] = mm[2] = 0.f;

    if (e < E) {
        const int s = src[e];
        const int d = dst[e];
        mm[0] = x[3 * s];     mm[1] = x[3 * s + 1]; mm[2] = x[3 * s + 2];
        mm[3] = x[3 * d];     mm[4] = x[3 * d + 1]; mm[5] = x[3 * d + 2];
        const float4 wv = ((const float4*)w)[e];
        mm[6] = wv.x; mm[7] = wv.y; mm[8] = wv.z; mm[9] = wv.w;

        a0 = sb2[0]; a1 = sb2[1]; a2 = sb2[2]; a3 = sb2[3];

        #pragma unroll
        for (int j = 0; j < 40; ++j) {
            const float4 r0 = *(const float4*)&sW1[j * 12];
            const float4 r1 = *(const float4*)&sW1[j * 12 + 4];
            const float2 r2 = *(const float2*)&sW1[j * 12 + 8];
            float hj = sb1[j];
            hj = fmaf(mm[0], r0.x, hj);
            hj = fmaf(mm[1], r0.y, hj);
            hj = fmaf(mm[2], r0.z, hj);
            hj = fmaf(mm[3], r0.w, hj);
            hj = fmaf(mm[4], r1.x, hj);
            hj = fmaf(mm[5], r1.y, hj);
            hj = fmaf(mm[6], r1.z, hj);
            hj = fmaf(mm[7], r1.w, hj);
            hj = fmaf(mm[8], r2.x, hj);
            hj = fmaf(mm[9], r2.y, hj);
            hj = fmaxf(hj, 0.f);
            const float4 w2 = *(const float4*)&sW2t[j * 4];
            a0 = fmaf(hj, w2.x, a0);
            a1 = fmaf(hj, w2.y, a1);
            a2 = fmaf(hj, w2.z, a2);
            a3 = fmaf(hj, w2.w, a3);
        }

        ((float4*)w_out)[e] = make_float4(a0, a1, a2, a3);
    }

    // Stage e_tilde row (x_src[0..2], w_out[0..3]) through LDS for coalesced stores.
    float* sw = s_et[wave];
    sw[lane * 7 + 0] = mm[0];
    sw[lane * 7 + 1] = mm[1];
    sw[lane * 7 + 2] = mm[2];
    sw[lane * 7 + 3] = a0;
    sw[lane * 7 + 4] = a1;
    sw[lane * 7 + 5] = a2;
    sw[lane * 7 + 6] = a3;
    __syncthreads();

    const int base_e = blockIdx.x * TPB + wave * 64;
    const int nvalid = (E - base_e < 64 ? (E - base_e) : 64) * 7; // floats valid in this wave
    const int fbase  = base_e * 7;
    #pragma unroll
    for (int k = 0; k < 7; ++k) {
        const int idx = lane + 64 * k;
        if (idx < nvalid) e_tilde[fbase + idx] = sw[idx];
    }
}

extern "C" void kernel_launch(void* const* d_in, const int* in_sizes, int n_in,
                              void* d_out, int out_size, void* d_ws, size_t ws_size,
                              hipStream_t stream) {
    const float* x  = (const float*)d_in[0];
    const float* w  = (const float*)d_in[1];
    const float* W1 = (const float*)d_in[2];
    const float* b1 = (const float*)d_in[3];
    const float* W2 = (const float*)d_in[4];
    const float* b2 = (const float*)d_in[5];
    const int* src  = (const int*)d_in[6];
    const int* dst  = (const int*)d_in[7];

    const int E = in_sizes[6];

    float* w_out   = (float*)d_out;
    float* e_tilde = w_out + (size_t)E * 4;

    const int nblocks = (E + TPB - 1) / TPB;
    edge_mlp_kernel<<<nblocks, TPB, 0, stream>>>(
        x, w, W1, b1, W2, b2, src, dst, w_out, e_tilde, E);
}